// Round 2
// baseline (246.326 us; speedup 1.0000x reference)
//
#include <hip/hip_runtime.h>
#include <hip/hip_bf16.h>

// DeformableConv1D: B=4, Cin=256, Cout=256, L=8192, K=7, stride=1, pad=3, dil=1
// out[b,o,l] = sum_{i,kt} w[o,i,kt] * interp(b, l, i, kt) + bias[o]
//
// Round 12: producer/consumer wave specialization.
//  - Round-11 post-mortem: deep gather prefetch in fused waves spilled
//    (WRITE_SIZE +19MB scratch). Fix: split roles so gather state and MFMA
//    state never share a wave's register budget.
//  - Waves 0..3: pure MFMA. 4 A-frags each (64 o) -> 16 MFMA per 4 ds_reads
//    (2x better LDS amortization than 8 waves x 2 frags). vmcnt queue holds
//    only Wf loads -> no ordering contortions.
//  - Waves 4..7: pure stagers. Thread owns kt=sw and kt=sw+4 (wave 7 single).
//    8-ch ping-pong gather (fX/fY) with 32-bit saddr offsets; cvt_pk pack.
//  - Double-buffered Il, 1 barrier/chunk, unchanged LDS layout.

#define B_    4
#define CIN   256
#define COUT  256
#define LEN   8192
#define KK    7
#define NTOT  (B_ * LEN)          // 32768 = 1<<15
#define QTOT  (CIN * KK)          // 1792
#define LPITCH 232                // LDS row pitch (elems); 464 B

typedef short s16x8 __attribute__((ext_vector_type(8)));
typedef int   s32x4 __attribute__((ext_vector_type(4)));
typedef float f32x4 __attribute__((ext_vector_type(4)));

static __device__ __forceinline__ unsigned f2bf(float f) {
  union { float f; unsigned u; } u; u.f = f;
  unsigned r = u.u + 0x7FFF + ((u.u >> 16) & 1);   // RNE (finite inputs)
  return r >> 16;
}

// packed pair: lo16 = bf16(a), hi16 = bf16(b); RNE, same bits as f2bf|f2bf<<16
static __device__ __forceinline__ int cvt_pk_bf16(float a, float b) {
  int r;
  asm("v_cvt_pk_bf16_f32 %0, %1, %2" : "=v"(r) : "v"(a), "v"(b));
  return r;
}

// ---------------------------------------------------------------------------
// Kernel 1: offset-conv partials. (unchanged)
// ---------------------------------------------------------------------------
__global__ __launch_bounds__(256) void loc_partial(
    const float* __restrict__ X, const float* __restrict__ OW,
    float* __restrict__ Partial) {
  __shared__ float red[4][256][KK];            // 28672 B

  const int t    = threadIdx.x;
  const int lane = t & 63;
  const int wu   = __builtin_amdgcn_readfirstlane(t >> 6);
  const int cg   = blockIdx.x >> 7;            // 0..3
  const int nb   = (blockIdx.x & 127) << 8;    // 256 n per block
  const int b    = nb >> 13;
  const int l0   = nb & (LEN - 1);

  float acc[KK][4];
#pragma unroll
  for (int k = 0; k < KK; ++k)
#pragma unroll
    for (int r = 0; r < 4; ++r) acc[k][r] = 0.0f;

#pragma unroll 2
  for (int ii = 0; ii < 16; ++ii) {
    const int i = cg * 64 + wu * 16 + ii;      // uniform
    float owv[49];
#pragma unroll
    for (int k = 0; k < KK; ++k)
#pragma unroll
      for (int j = 0; j < KK; ++j)
        owv[k * 7 + j] = OW[(k * CIN + i) * KK + j];   // uniform -> s_load

    const float* xr = X + ((size_t)(b * CIN + i) << 13);
#pragma unroll
    for (int r = 0; r < 4; ++r) {
      const int lr = l0 + lane + 64 * r;
      float xv[KK];
#pragma unroll
      for (int j = 0; j < KK; ++j) {
        int pos = lr + j - 3;
        xv[j] = ((unsigned)pos < LEN) ? xr[pos] : 0.0f;
      }
#pragma unroll
      for (int k = 0; k < KK; ++k)
#pragma unroll
        for (int j = 0; j < KK; ++j)
          acc[k][r] += xv[j] * owv[k * 7 + j];
    }
  }

#pragma unroll
  for (int k = 0; k < KK; ++k)
#pragma unroll
    for (int r = 0; r < 4; ++r) red[wu][lane + 64 * r][k] = acc[k][r];
  __syncthreads();

#pragma unroll
  for (int k = 0; k < KK; ++k) {
    float s = red[0][t][k] + red[1][t][k] + red[2][t][k] + red[3][t][k];
    Partial[((size_t)(cg * 7 + k) << 15) + nb + t] = s;   // coalesced
  }
}

// ---------------------------------------------------------------------------
// Kernel 2: Loc[k][n] = (l+k) + OB[k] + sum_cg Partial[cg*7+k][n] (unchanged)
// ---------------------------------------------------------------------------
__global__ __launch_bounds__(256) void loc_reduce(
    const float* __restrict__ Partial, const float* __restrict__ OB,
    float* __restrict__ Loc) {
  int n = blockIdx.x * 256 + threadIdx.x;      // grid 128 -> 32768
  int l = n & (LEN - 1);
#pragma unroll
  for (int k = 0; k < KK; ++k) {
    float s = (float)(l + k) + OB[k];
#pragma unroll
    for (int cg = 0; cg < 4; ++cg)
      s += Partial[((size_t)(cg * 7 + k) << 15) + n];
    Loc[((size_t)k << 15) + n] = s;
  }
}

// ---------------------------------------------------------------------------
// Kernel 3: weights -> bf16 A-fragments via LDS. (unchanged)
// ---------------------------------------------------------------------------
__global__ __launch_bounds__(256) void wt_build(
    const float* __restrict__ W, unsigned short* __restrict__ Wf) {
  __shared__ float Wl[16 * 32 * KK];           // 14336 B
  const int t  = threadIdx.x;
  const int ot = blockIdx.x >> 3;
  const int c  = blockIdx.x & 7;

  for (int e = t; e < 16 * 32 * KK; e += 256) {
    int o = e / 224;
    int r = e - o * 224;
    Wl[e] = W[(size_t)(ot * 16 + o) * QTOT + c * 224 + r];
  }
  __syncthreads();

  const int lane = t & 63;
  const int sg   = t >> 6;
  const int ol   = lane & 15;
  const int ig   = lane >> 4;
  for (int s = sg; s < KK; s += 4) {
    s16x8 v;
#pragma unroll
    for (int j = 0; j < 8; ++j)
      v[j] = (short)f2bf(Wl[ol * 224 + (ig * 8 + j) * KK + s]);
    int f = (ot * 8 + c) * KK + s;
    *(s16x8*)(Wf + ((size_t)f << 9) + (lane << 3)) = v;
  }
}

// ---------------------------------------------------------------------------
// Kernel 4: main MFMA GEMM, wave-specialized.
// Block = 512 threads (8 waves), 256 o x 64 n, grid 512.
// Waves 0..3 consume (16 MFMA / 4 ds_read_b128 per K-step);
// waves 4..7 produce (gather+interp+pack chunk c+1 into Inxt).
// ---------------------------------------------------------------------------
__global__ __launch_bounds__(512, 4) void main_kernel(
    const float* __restrict__ X, const unsigned short* __restrict__ Wf,
    const float* __restrict__ Bias, const float* __restrict__ Loc,
    float* __restrict__ Out) {
  __shared__ unsigned short Il[2][64][LPITCH];   // 59392 B

  const int t    = threadIdx.x;
  const int lane = t & 63;
  const int w    = __builtin_amdgcn_readfirstlane(t >> 6);   // 0..7
  const int n0   = blockIdx.x << 6;            // grid 512
  const int b    = n0 >> 13;
  const float* Xb = X + ((size_t)b << 21);

  const int mrow = lane & 15;
  const int quad = lane >> 4;
  const bool mf  = (w < 4);                    // MFMA role

  // ---- stager state (waves 4..7) ----
  const int sw   = w - 4;                      // 0..3 when stager
  const int nl   = lane;
  const int ktA  = sw;                         // stream A: kt 0..3
  const int ktB  = sw + 4;                     // stream B: kt 4..6 (7 -> none)
  const bool hasB = (!mf) && (ktB < KK);

  float c0A = 0.f, c1A = 0.f, c0B = 0.f, c1B = 0.f;
  int offA = 0, offB = 0;                      // 32-bit elem offsets from Xb
  if (!mf) {
    {
      float locv = Loc[((size_t)ktA << 15) + n0 + nl];
      int x0  = (int)floorf(locv);
      int x0c = min(max(x0, 0), LEN - 1);
      int x1c = min(max(x0 + 1, 0), LEN - 1);
      float wa = (float)x1c - locv;
      float wb = locv - (float)x0c;
      bool hi = (x0 >= LEN - 1), lo = (x0 < 0);
      c0A = (hi ? 0.f : wa) + (lo ? wb : 0.f);
      c1A = (hi ? wa : 0.f) + (lo ? 0.f : wb);
      offA = min(max(x0, 0), LEN - 2);
    }
    if (hasB) {
      float locv = Loc[((size_t)ktB << 15) + n0 + nl];
      int x0  = (int)floorf(locv);
      int x0c = min(max(x0, 0), LEN - 1);
      int x1c = min(max(x0 + 1, 0), LEN - 1);
      float wa = (float)x1c - locv;
      float wb = locv - (float)x0c;
      bool hi = (x0 >= LEN - 1), lo = (x0 < 0);
      c0B = (hi ? 0.f : wa) + (lo ? wb : 0.f);
      c1B = (hi ? wa : 0.f) + (lo ? 0.f : wb);
      offB = min(max(x0, 0), LEN - 2);
    }
  }

  f32x4 acc[4][4];                             // MFMA waves only
  if (mf) {
#pragma unroll
    for (int a = 0; a < 4; ++a)
#pragma unroll
      for (int cc = 0; cc < 4; ++cc) acc[a][cc] = (f32x4){0.f, 0.f, 0.f, 0.f};
  }

  float fX0[8], fX1[8], fY0[8], fY1[8];        // stager ping-pong sets

// gather one 8-ch quarter of stream st=(j>>2) into F0/F1 (saddr + 32b voffset)
#define GQ(j, F0, F1) {                                               \
    const int st_ = (j) >> 2; const int hh_ = (j) & 3;                \
    if (st_ == 0 || hasB) {                                           \
      const int o_ = st_ ? offBc : offAc;                             \
      _Pragma("unroll")                                               \
      for (int m = 0; m < 8; ++m) {                                   \
        const int idx = o_ + ((hh_ * 8 + m) << 13);                   \
        F0[m] = Xb[idx];                                              \
        F1[m] = Xb[idx + 1];                                          \
      }                                                               \
    } }

// interp + pack one quarter -> one b128 LDS write
#define CQ(j, F0, F1, DST) {                                          \
    const int st_ = (j) >> 2; const int hh_ = (j) & 3;                \
    if (st_ == 0 || hasB) {                                           \
      const float c0_ = st_ ? c0B : c0A;                              \
      const float c1_ = st_ ? c1B : c1A;                              \
      const int   kt_ = st_ ? ktB : ktA;                              \
      s32x4 vv;                                                       \
      _Pragma("unroll")                                               \
      for (int m = 0; m < 4; ++m) {                                   \
        float a = c0_ * F0[2 * m]     + c1_ * F1[2 * m];              \
        float d = c0_ * F0[2 * m + 1] + c1_ * F1[2 * m + 1];          \
        vv[m] = cvt_pk_bf16(a, d);                                    \
      }                                                               \
      *(s32x4*)((DST) + nl * LPITCH + kt_ * 32 + hh_ * 8) = vv;       \
    } }

// stage a full 32-ch chunk (both streams), ping-pong X/Y gather sets
#define STAGE(DST, CH0) {                                             \
    const int offAc = offA + ((CH0) << 13);                           \
    const int offBc = offB + ((CH0) << 13);                           \
    GQ(0, fX0, fX1) GQ(1, fY0, fY1)                                   \
    CQ(0, fX0, fX1, DST) GQ(2, fX0, fX1)                              \
    CQ(1, fY0, fY1, DST) GQ(3, fY0, fY1)                              \
    CQ(2, fX0, fX1, DST) GQ(4, fX0, fX1)                              \
    CQ(3, fY0, fY1, DST) GQ(5, fY0, fY1)                              \
    CQ(4, fX0, fX1, DST) GQ(6, fX0, fX1)                              \
    CQ(5, fY0, fY1, DST) GQ(7, fY0, fY1)                              \
    CQ(6, fX0, fX1, DST)                                              \
    CQ(7, fY0, fY1, DST)                                              \
  }

#define AFL(ttv, sv)                                                  \
  (*(const s16x8*)(Wf + ((size_t)(((w * 4 + (ttv)) * 8 + c) * KK + (sv)) << 9) + (lane << 3)))

#define BLD(ro, sv)                                                   \
  (*(const s16x8*)(Icur + ((ro) + mrow) * LPITCH + (sv) * 32 + quad * 8))

#define MSTEP4(sv) {                                                  \
    const s16x8 a0 = AFL(0, sv), a1 = AFL(1, sv);                     \
    const s16x8 a2 = AFL(2, sv), a3 = AFL(3, sv);                     \
    const s16x8 b0 = BLD(0, sv), b1 = BLD(16, sv);                    \
    acc[0][0] = __builtin_amdgcn_mfma_f32_16x16x32_bf16(a0, b0, acc[0][0], 0, 0, 0); \
    acc[1][0] = __builtin_amdgcn_mfma_f32_16x16x32_bf16(a1, b0, acc[1][0], 0, 0, 0); \
    acc[2][0] = __builtin_amdgcn_mfma_f32_16x16x32_bf16(a2, b0, acc[2][0], 0, 0, 0); \
    acc[3][0] = __builtin_amdgcn_mfma_f32_16x16x32_bf16(a3, b0, acc[3][0], 0, 0, 0); \
    acc[0][1] = __builtin_amdgcn_mfma_f32_16x16x32_bf16(a0, b1, acc[0][1], 0, 0, 0); \
    acc[1][1] = __builtin_amdgcn_mfma_f32_16x16x32_bf16(a1, b1, acc[1][1], 0, 0, 0); \
    acc[2][1] = __builtin_amdgcn_mfma_f32_16x16x32_bf16(a2, b1, acc[2][1], 0, 0, 0); \
    acc[3][1] = __builtin_amdgcn_mfma_f32_16x16x32_bf16(a3, b1, acc[3][1], 0, 0, 0); \
    const s16x8 b2 = BLD(32, sv), b3 = BLD(48, sv);                   \
    acc[0][2] = __builtin_amdgcn_mfma_f32_16x16x32_bf16(a0, b2, acc[0][2], 0, 0, 0); \
    acc[1][2] = __builtin_amdgcn_mfma_f32_16x16x32_bf16(a1, b2, acc[1][2], 0, 0, 0); \
    acc[2][2] = __builtin_amdgcn_mfma_f32_16x16x32_bf16(a2, b2, acc[2][2], 0, 0, 0); \
    acc[3][2] = __builtin_amdgcn_mfma_f32_16x16x32_bf16(a3, b2, acc[3][2], 0, 0, 0); \
    acc[0][3] = __builtin_amdgcn_mfma_f32_16x16x32_bf16(a0, b3, acc[0][3], 0, 0, 0); \
    acc[1][3] = __builtin_amdgcn_mfma_f32_16x16x32_bf16(a1, b3, acc[1][3], 0, 0, 0); \
    acc[2][3] = __builtin_amdgcn_mfma_f32_16x16x32_bf16(a2, b3, acc[2][3], 0, 0, 0); \
    acc[3][3] = __builtin_amdgcn_mfma_f32_16x16x32_bf16(a3, b3, acc[3][3], 0, 0, 0); \
  }

  // prologue: stagers fill Il[0] with chunk 0; MFMA waves wait
  if (!mf) { STAGE(&Il[0][0][0], 0) }
  __syncthreads();

  for (int c = 0; c < 8; ++c) {
    if (mf) {
      const unsigned short* Icur = &Il[c & 1][0][0];
      MSTEP4(0) MSTEP4(1) MSTEP4(2) MSTEP4(3) MSTEP4(4) MSTEP4(5) MSTEP4(6)
    } else if (c < 7) {
      unsigned short* Inxt = &Il[(c & 1) ^ 1][0][0];
      STAGE(Inxt, (c + 1) * 32)
    }
    __syncthreads();
  }
#undef GQ
#undef CQ
#undef STAGE
#undef AFL
#undef BLD
#undef MSTEP4

  // epilogue (MFMA waves): D row m = quad*4+r (o), col = mrow (l)
  if (mf) {
    const int lbase = (n0 & (LEN - 1)) + mrow;
#pragma unroll
    for (int tt = 0; tt < 4; ++tt) {
      const int obase = (w * 4 + tt) * 16 + quad * 4;
#pragma unroll
      for (int r = 0; r < 4; ++r) {
        const int o = obase + r;
        const float bv = Bias[o];
        float* orow = Out + (((size_t)(b * COUT + o)) << 13) + lbase;
#pragma unroll
        for (int nt = 0; nt < 4; ++nt)
          orow[nt * 16] = acc[tt][nt][r] + bv;
      }
    }
  }
}

extern "C" void kernel_launch(void* const* d_in, const int* in_sizes, int n_in,
                              void* d_out, int out_size, void* d_ws, size_t ws_size,
                              hipStream_t stream) {
  const float* X    = (const float*)d_in[0];   // (4,256,8192)
  const float* W    = (const float*)d_in[1];   // (256,256,7)
  const float* Bias = (const float*)d_in[2];   // (256,)
  const float* OW   = (const float*)d_in[3];   // (7,256,7)
  const float* OB   = (const float*)d_in[4];   // (7,)
  float* Out = (float*)d_out;                  // (4,256,8192)

  // ws: Loc (0.92 MB) | Wf (0.92 MB) | Partial (3.5 MB)  = 5.4 MB
  float* Loc = (float*)d_ws;
  unsigned short* Wf = (unsigned short*)(Loc + (size_t)NTOT * KK);
  float* Partial = (float*)(Wf + (size_t)COUT * QTOT);

  loc_partial<<<4 * 128, 256, 0, stream>>>(X, OW, Partial);
  loc_reduce<<<NTOT / 256, 256, 0, stream>>>(Partial, OB, Loc);
  wt_build<<<128, 256, 0, stream>>>(W, Wf);
  main_kernel<<<NTOT / 64, 512, 0, stream>>>(X, Wf, Bias, Loc, Out);
}

// Round 3
// 182.238 us; speedup vs baseline: 1.3517x; 1.3517x over previous
//
#include <hip/hip_runtime.h>
#include <hip/hip_bf16.h>

// DeformableConv1D: B=4, Cin=256, Cout=256, L=8192, K=7, stride=1, pad=3, dil=1
// out[b,o,l] = sum_{i,kt} w[o,i,kt] * interp(b, l, i, kt) + bias[o]
//
// Round 13 = Round 12 + the register-cap fix.
//  - Post-mortem r12: __launch_bounds__(512,4) is honored as 4 BLOCKS/CU
//    (CUDA semantics) -> 32 waves/CU -> 64-VGPR cap. acc[4][4] (64 regs,
//    live across the loop) + stager state could not fit -> accumulator
//    spilled to scratch (WRITE_SIZE 354MB). Grid is exactly 2 blocks/CU,
//    so demanding 4 was pure loss. (512,2) -> 128-VGPR cap, same real
//    occupancy.
//  - Waves 0..3: pure MFMA (16 MFMA per 4 ds_read_b128).
//  - Waves 4..7: pure stagers (8-ch ping-pong gather, cvt_pk pack).
//  - Double-buffered Il, 1 barrier/chunk.

#define B_    4
#define CIN   256
#define COUT  256
#define LEN   8192
#define KK    7
#define NTOT  (B_ * LEN)          // 32768 = 1<<15
#define QTOT  (CIN * KK)          // 1792
#define LPITCH 232                // LDS row pitch (elems); 464 B

typedef short s16x8 __attribute__((ext_vector_type(8)));
typedef int   s32x4 __attribute__((ext_vector_type(4)));
typedef float f32x4 __attribute__((ext_vector_type(4)));

static __device__ __forceinline__ unsigned f2bf(float f) {
  union { float f; unsigned u; } u; u.f = f;
  unsigned r = u.u + 0x7FFF + ((u.u >> 16) & 1);   // RNE (finite inputs)
  return r >> 16;
}

// packed pair: lo16 = bf16(a), hi16 = bf16(b); RNE, same bits as f2bf|f2bf<<16
static __device__ __forceinline__ int cvt_pk_bf16(float a, float b) {
  int r;
  asm("v_cvt_pk_bf16_f32 %0, %1, %2" : "=v"(r) : "v"(a), "v"(b));
  return r;
}

// ---------------------------------------------------------------------------
// Kernel 1: offset-conv partials. (unchanged)
// ---------------------------------------------------------------------------
__global__ __launch_bounds__(256) void loc_partial(
    const float* __restrict__ X, const float* __restrict__ OW,
    float* __restrict__ Partial) {
  __shared__ float red[4][256][KK];            // 28672 B

  const int t    = threadIdx.x;
  const int lane = t & 63;
  const int wu   = __builtin_amdgcn_readfirstlane(t >> 6);
  const int cg   = blockIdx.x >> 7;            // 0..3
  const int nb   = (blockIdx.x & 127) << 8;    // 256 n per block
  const int b    = nb >> 13;
  const int l0   = nb & (LEN - 1);

  float acc[KK][4];
#pragma unroll
  for (int k = 0; k < KK; ++k)
#pragma unroll
    for (int r = 0; r < 4; ++r) acc[k][r] = 0.0f;

#pragma unroll 2
  for (int ii = 0; ii < 16; ++ii) {
    const int i = cg * 64 + wu * 16 + ii;      // uniform
    float owv[49];
#pragma unroll
    for (int k = 0; k < KK; ++k)
#pragma unroll
      for (int j = 0; j < KK; ++j)
        owv[k * 7 + j] = OW[(k * CIN + i) * KK + j];   // uniform -> s_load

    const float* xr = X + ((size_t)(b * CIN + i) << 13);
#pragma unroll
    for (int r = 0; r < 4; ++r) {
      const int lr = l0 + lane + 64 * r;
      float xv[KK];
#pragma unroll
      for (int j = 0; j < KK; ++j) {
        int pos = lr + j - 3;
        xv[j] = ((unsigned)pos < LEN) ? xr[pos] : 0.0f;
      }
#pragma unroll
      for (int k = 0; k < KK; ++k)
#pragma unroll
        for (int j = 0; j < KK; ++j)
          acc[k][r] += xv[j] * owv[k * 7 + j];
    }
  }

#pragma unroll
  for (int k = 0; k < KK; ++k)
#pragma unroll
    for (int r = 0; r < 4; ++r) red[wu][lane + 64 * r][k] = acc[k][r];
  __syncthreads();

#pragma unroll
  for (int k = 0; k < KK; ++k) {
    float s = red[0][t][k] + red[1][t][k] + red[2][t][k] + red[3][t][k];
    Partial[((size_t)(cg * 7 + k) << 15) + nb + t] = s;   // coalesced
  }
}

// ---------------------------------------------------------------------------
// Kernel 2: Loc[k][n] = (l+k) + OB[k] + sum_cg Partial[cg*7+k][n] (unchanged)
// ---------------------------------------------------------------------------
__global__ __launch_bounds__(256) void loc_reduce(
    const float* __restrict__ Partial, const float* __restrict__ OB,
    float* __restrict__ Loc) {
  int n = blockIdx.x * 256 + threadIdx.x;      // grid 128 -> 32768
  int l = n & (LEN - 1);
#pragma unroll
  for (int k = 0; k < KK; ++k) {
    float s = (float)(l + k) + OB[k];
#pragma unroll
    for (int cg = 0; cg < 4; ++cg)
      s += Partial[((size_t)(cg * 7 + k) << 15) + n];
    Loc[((size_t)k << 15) + n] = s;
  }
}

// ---------------------------------------------------------------------------
// Kernel 3: weights -> bf16 A-fragments via LDS. (unchanged)
// ---------------------------------------------------------------------------
__global__ __launch_bounds__(256) void wt_build(
    const float* __restrict__ W, unsigned short* __restrict__ Wf) {
  __shared__ float Wl[16 * 32 * KK];           // 14336 B
  const int t  = threadIdx.x;
  const int ot = blockIdx.x >> 3;
  const int c  = blockIdx.x & 7;

  for (int e = t; e < 16 * 32 * KK; e += 256) {
    int o = e / 224;
    int r = e - o * 224;
    Wl[e] = W[(size_t)(ot * 16 + o) * QTOT + c * 224 + r];
  }
  __syncthreads();

  const int lane = t & 63;
  const int sg   = t >> 6;
  const int ol   = lane & 15;
  const int ig   = lane >> 4;
  for (int s = sg; s < KK; s += 4) {
    s16x8 v;
#pragma unroll
    for (int j = 0; j < 8; ++j)
      v[j] = (short)f2bf(Wl[ol * 224 + (ig * 8 + j) * KK + s]);
    int f = (ot * 8 + c) * KK + s;
    *(s16x8*)(Wf + ((size_t)f << 9) + (lane << 3)) = v;
  }
}

// ---------------------------------------------------------------------------
// Kernel 4: main MFMA GEMM, wave-specialized.
// Block = 512 threads (8 waves), 256 o x 64 n, grid 512 (= 2 blocks/CU).
// Waves 0..3 consume (16 MFMA / 4 ds_read_b128 per K-step);
// waves 4..7 produce (gather+interp+pack chunk c+1 into Inxt).
// launch_bounds (512,2): 2 blocks/CU -> 128-VGPR cap (acc must stay in regs).
// ---------------------------------------------------------------------------
__global__ __launch_bounds__(512, 2) void main_kernel(
    const float* __restrict__ X, const unsigned short* __restrict__ Wf,
    const float* __restrict__ Bias, const float* __restrict__ Loc,
    float* __restrict__ Out) {
  __shared__ unsigned short Il[2][64][LPITCH];   // 59392 B

  const int t    = threadIdx.x;
  const int lane = t & 63;
  const int w    = __builtin_amdgcn_readfirstlane(t >> 6);   // 0..7
  const int n0   = blockIdx.x << 6;            // grid 512
  const int b    = n0 >> 13;
  const float* Xb = X + ((size_t)b << 21);

  const int mrow = lane & 15;
  const int quad = lane >> 4;
  const bool mf  = (w < 4);                    // MFMA role

  // ---- stager state (waves 4..7) ----
  const int sw   = w - 4;                      // 0..3 when stager
  const int nl   = lane;
  const int ktA  = sw;                         // stream A: kt 0..3
  const int ktB  = sw + 4;                     // stream B: kt 4..6 (7 -> none)
  const bool hasB = (!mf) && (ktB < KK);

  float c0A = 0.f, c1A = 0.f, c0B = 0.f, c1B = 0.f;
  int offA = 0, offB = 0;                      // 32-bit elem offsets from Xb
  if (!mf) {
    {
      float locv = Loc[((size_t)ktA << 15) + n0 + nl];
      int x0  = (int)floorf(locv);
      int x0c = min(max(x0, 0), LEN - 1);
      int x1c = min(max(x0 + 1, 0), LEN - 1);
      float wa = (float)x1c - locv;
      float wb = locv - (float)x0c;
      bool hi = (x0 >= LEN - 1), lo = (x0 < 0);
      c0A = (hi ? 0.f : wa) + (lo ? wb : 0.f);
      c1A = (hi ? wa : 0.f) + (lo ? 0.f : wb);
      offA = min(max(x0, 0), LEN - 2);
    }
    if (hasB) {
      float locv = Loc[((size_t)ktB << 15) + n0 + nl];
      int x0  = (int)floorf(locv);
      int x0c = min(max(x0, 0), LEN - 1);
      int x1c = min(max(x0 + 1, 0), LEN - 1);
      float wa = (float)x1c - locv;
      float wb = locv - (float)x0c;
      bool hi = (x0 >= LEN - 1), lo = (x0 < 0);
      c0B = (hi ? 0.f : wa) + (lo ? wb : 0.f);
      c1B = (hi ? wa : 0.f) + (lo ? 0.f : wb);
      offB = min(max(x0, 0), LEN - 2);
    }
  }

  f32x4 acc[4][4];                             // MFMA waves only
  if (mf) {
#pragma unroll
    for (int a = 0; a < 4; ++a)
#pragma unroll
      for (int cc = 0; cc < 4; ++cc) acc[a][cc] = (f32x4){0.f, 0.f, 0.f, 0.f};
  }

  float fX0[8], fX1[8], fY0[8], fY1[8];        // stager ping-pong sets

// gather one 8-ch quarter of stream st=(j>>2) into F0/F1 (saddr + 32b voffset)
#define GQ(j, F0, F1) {                                               \
    const int st_ = (j) >> 2; const int hh_ = (j) & 3;                \
    if (st_ == 0 || hasB) {                                           \
      const int o_ = st_ ? offBc : offAc;                             \
      _Pragma("unroll")                                               \
      for (int m = 0; m < 8; ++m) {                                   \
        const int idx = o_ + ((hh_ * 8 + m) << 13);                   \
        F0[m] = Xb[idx];                                              \
        F1[m] = Xb[idx + 1];                                          \
      }                                                               \
    } }

// interp + pack one quarter -> one b128 LDS write
#define CQ(j, F0, F1, DST) {                                          \
    const int st_ = (j) >> 2; const int hh_ = (j) & 3;                \
    if (st_ == 0 || hasB) {                                           \
      const float c0_ = st_ ? c0B : c0A;                              \
      const float c1_ = st_ ? c1B : c1A;                              \
      const int   kt_ = st_ ? ktB : ktA;                              \
      s32x4 vv;                                                       \
      _Pragma("unroll")                                               \
      for (int m = 0; m < 4; ++m) {                                   \
        float a = c0_ * F0[2 * m]     + c1_ * F1[2 * m];              \
        float d = c0_ * F0[2 * m + 1] + c1_ * F1[2 * m + 1];          \
        vv[m] = cvt_pk_bf16(a, d);                                    \
      }                                                               \
      *(s32x4*)((DST) + nl * LPITCH + kt_ * 32 + hh_ * 8) = vv;       \
    } }

// stage a full 32-ch chunk (both streams), ping-pong X/Y gather sets
#define STAGE(DST, CH0) {                                             \
    const int offAc = offA + ((CH0) << 13);                           \
    const int offBc = offB + ((CH0) << 13);                           \
    GQ(0, fX0, fX1) GQ(1, fY0, fY1)                                   \
    CQ(0, fX0, fX1, DST) GQ(2, fX0, fX1)                              \
    CQ(1, fY0, fY1, DST) GQ(3, fY0, fY1)                              \
    CQ(2, fX0, fX1, DST) GQ(4, fX0, fX1)                              \
    CQ(3, fY0, fY1, DST) GQ(5, fY0, fY1)                              \
    CQ(4, fX0, fX1, DST) GQ(6, fX0, fX1)                              \
    CQ(5, fY0, fY1, DST) GQ(7, fY0, fY1)                              \
    CQ(6, fX0, fX1, DST)                                              \
    CQ(7, fY0, fY1, DST)                                              \
  }

#define AFL(ttv, sv)                                                  \
  (*(const s16x8*)(Wf + ((size_t)(((w * 4 + (ttv)) * 8 + c) * KK + (sv)) << 9) + (lane << 3)))

#define BLD(ro, sv)                                                   \
  (*(const s16x8*)(Icur + ((ro) + mrow) * LPITCH + (sv) * 32 + quad * 8))

#define MSTEP4(sv) {                                                  \
    const s16x8 a0 = AFL(0, sv), a1 = AFL(1, sv);                     \
    const s16x8 a2 = AFL(2, sv), a3 = AFL(3, sv);                     \
    const s16x8 b0 = BLD(0, sv), b1 = BLD(16, sv);                    \
    acc[0][0] = __builtin_amdgcn_mfma_f32_16x16x32_bf16(a0, b0, acc[0][0], 0, 0, 0); \
    acc[1][0] = __builtin_amdgcn_mfma_f32_16x16x32_bf16(a1, b0, acc[1][0], 0, 0, 0); \
    acc[2][0] = __builtin_amdgcn_mfma_f32_16x16x32_bf16(a2, b0, acc[2][0], 0, 0, 0); \
    acc[3][0] = __builtin_amdgcn_mfma_f32_16x16x32_bf16(a3, b0, acc[3][0], 0, 0, 0); \
    acc[0][1] = __builtin_amdgcn_mfma_f32_16x16x32_bf16(a0, b1, acc[0][1], 0, 0, 0); \
    acc[1][1] = __builtin_amdgcn_mfma_f32_16x16x32_bf16(a1, b1, acc[1][1], 0, 0, 0); \
    acc[2][1] = __builtin_amdgcn_mfma_f32_16x16x32_bf16(a2, b1, acc[2][1], 0, 0, 0); \
    acc[3][1] = __builtin_amdgcn_mfma_f32_16x16x32_bf16(a3, b1, acc[3][1], 0, 0, 0); \
    const s16x8 b2 = BLD(32, sv), b3 = BLD(48, sv);                   \
    acc[0][2] = __builtin_amdgcn_mfma_f32_16x16x32_bf16(a0, b2, acc[0][2], 0, 0, 0); \
    acc[1][2] = __builtin_amdgcn_mfma_f32_16x16x32_bf16(a1, b2, acc[1][2], 0, 0, 0); \
    acc[2][2] = __builtin_amdgcn_mfma_f32_16x16x32_bf16(a2, b2, acc[2][2], 0, 0, 0); \
    acc[3][2] = __builtin_amdgcn_mfma_f32_16x16x32_bf16(a3, b2, acc[3][2], 0, 0, 0); \
    acc[0][3] = __builtin_amdgcn_mfma_f32_16x16x32_bf16(a0, b3, acc[0][3], 0, 0, 0); \
    acc[1][3] = __builtin_amdgcn_mfma_f32_16x16x32_bf16(a1, b3, acc[1][3], 0, 0, 0); \
    acc[2][3] = __builtin_amdgcn_mfma_f32_16x16x32_bf16(a2, b3, acc[2][3], 0, 0, 0); \
    acc[3][3] = __builtin_amdgcn_mfma_f32_16x16x32_bf16(a3, b3, acc[3][3], 0, 0, 0); \
  }

  // prologue: stagers fill Il[0] with chunk 0; MFMA waves wait
  if (!mf) { STAGE(&Il[0][0][0], 0) }
  __syncthreads();

  for (int c = 0; c < 8; ++c) {
    if (mf) {
      const unsigned short* Icur = &Il[c & 1][0][0];
      MSTEP4(0) MSTEP4(1) MSTEP4(2) MSTEP4(3) MSTEP4(4) MSTEP4(5) MSTEP4(6)
    } else if (c < 7) {
      unsigned short* Inxt = &Il[(c & 1) ^ 1][0][0];
      STAGE(Inxt, (c + 1) * 32)
    }
    __syncthreads();
  }
#undef GQ
#undef CQ
#undef STAGE
#undef AFL
#undef BLD
#undef MSTEP4

  // epilogue (MFMA waves): D row m = quad*4+r (o), col = mrow (l)
  if (mf) {
    const int lbase = (n0 & (LEN - 1)) + mrow;
#pragma unroll
    for (int tt = 0; tt < 4; ++tt) {
      const int obase = (w * 4 + tt) * 16 + quad * 4;
#pragma unroll
      for (int r = 0; r < 4; ++r) {
        const int o = obase + r;
        const float bv = Bias[o];
        float* orow = Out + (((size_t)(b * COUT + o)) << 13) + lbase;
#pragma unroll
        for (int nt = 0; nt < 4; ++nt)
          orow[nt * 16] = acc[tt][nt][r] + bv;
      }
    }
  }
}

extern "C" void kernel_launch(void* const* d_in, const int* in_sizes, int n_in,
                              void* d_out, int out_size, void* d_ws, size_t ws_size,
                              hipStream_t stream) {
  const float* X    = (const float*)d_in[0];   // (4,256,8192)
  const float* W    = (const float*)d_in[1];   // (256,256,7)
  const float* Bias = (const float*)d_in[2];   // (256,)
  const float* OW   = (const float*)d_in[3];   // (7,256,7)
  const float* OB   = (const float*)d_in[4];   // (7,)
  float* Out = (float*)d_out;                  // (4,256,8192)

  // ws: Loc (0.92 MB) | Wf (0.92 MB) | Partial (3.5 MB)  = 5.4 MB
  float* Loc = (float*)d_ws;
  unsigned short* Wf = (unsigned short*)(Loc + (size_t)NTOT * KK);
  float* Partial = (float*)(Wf + (size_t)COUT * QTOT);

  loc_partial<<<4 * 128, 256, 0, stream>>>(X, OW, Partial);
  loc_reduce<<<NTOT / 256, 256, 0, stream>>>(Partial, OB, Loc);
  wt_build<<<128, 256, 0, stream>>>(W, Wf);
  main_kernel<<<NTOT / 64, 512, 0, stream>>>(X, Wf, Bias, Loc, Out);
}

// Round 4
// 172.751 us; speedup vs baseline: 1.4259x; 1.0549x over previous
//
#include <hip/hip_runtime.h>
#include <hip/hip_bf16.h>

// DeformableConv1D: B=4, Cin=256, Cout=256, L=8192, K=7, stride=1, pad=3, dil=1
// out[b,o,l] = sum_{i,kt} w[o,i,kt] * interp(b, l, i, kt) + bias[o]
//
// Round 14 = Round 10's fused schedule (best measured: 64.6us) + two fixes
// each validated in isolation during r11-r13:
//  - __launch_bounds__(512,2): r10/r11 ran under a 64-VGPR cap ((512,4) =
//    4 blocks/CU demanded; grid is exactly 2 blocks/CU and LDS fits only 2,
//    so the extra demand bought nothing and forced a ~3MB scratch spill).
//    r13 proved (512,2) -> 128-VGPR cap, spill-free (WRITE back to 32.8MB).
//  - v_cvt_pk_bf16_f32 pack (bit-identical RNE, r11-verified) replaces the
//    4-VALU manual f2bf pair in the hot CVT path.
// Schedule itself is byte-for-byte r10: fused waves, af-frags loaded before
// gathers each chunk (sched_barrier pinned), gathers in 8-ch quarters
// interleaved between MFMA K-steps, double-buffered Il, 1 barrier/chunk.

#define B_    4
#define CIN   256
#define COUT  256
#define LEN   8192
#define KK    7
#define NTOT  (B_ * LEN)          // 32768 = 1<<15
#define QTOT  (CIN * KK)          // 1792
#define LPITCH 232                // LDS row pitch (elems); 464 B

typedef short s16x8 __attribute__((ext_vector_type(8)));
typedef int   s32x4 __attribute__((ext_vector_type(4)));
typedef float f32x4 __attribute__((ext_vector_type(4)));

static __device__ __forceinline__ unsigned f2bf(float f) {
  union { float f; unsigned u; } u; u.f = f;
  unsigned r = u.u + 0x7FFF + ((u.u >> 16) & 1);   // RNE (finite inputs)
  return r >> 16;
}

// packed pair: lo16 = bf16(a), hi16 = bf16(b); RNE, same bits as f2bf|f2bf<<16
static __device__ __forceinline__ int cvt_pk_bf16(float a, float b) {
  int r;
  asm("v_cvt_pk_bf16_f32 %0, %1, %2" : "=v"(r) : "v"(a), "v"(b));
  return r;
}

// ---------------------------------------------------------------------------
// Kernel 1: offset-conv partials. (unchanged)
// ---------------------------------------------------------------------------
__global__ __launch_bounds__(256) void loc_partial(
    const float* __restrict__ X, const float* __restrict__ OW,
    float* __restrict__ Partial) {
  __shared__ float red[4][256][KK];            // 28672 B

  const int t    = threadIdx.x;
  const int lane = t & 63;
  const int wu   = __builtin_amdgcn_readfirstlane(t >> 6);
  const int cg   = blockIdx.x >> 7;            // 0..3
  const int nb   = (blockIdx.x & 127) << 8;    // 256 n per block
  const int b    = nb >> 13;
  const int l0   = nb & (LEN - 1);

  float acc[KK][4];
#pragma unroll
  for (int k = 0; k < KK; ++k)
#pragma unroll
    for (int r = 0; r < 4; ++r) acc[k][r] = 0.0f;

#pragma unroll 2
  for (int ii = 0; ii < 16; ++ii) {
    const int i = cg * 64 + wu * 16 + ii;      // uniform
    float owv[49];
#pragma unroll
    for (int k = 0; k < KK; ++k)
#pragma unroll
      for (int j = 0; j < KK; ++j)
        owv[k * 7 + j] = OW[(k * CIN + i) * KK + j];   // uniform -> s_load

    const float* xr = X + ((size_t)(b * CIN + i) << 13);
#pragma unroll
    for (int r = 0; r < 4; ++r) {
      const int lr = l0 + lane + 64 * r;
      float xv[KK];
#pragma unroll
      for (int j = 0; j < KK; ++j) {
        int pos = lr + j - 3;
        xv[j] = ((unsigned)pos < LEN) ? xr[pos] : 0.0f;
      }
#pragma unroll
      for (int k = 0; k < KK; ++k)
#pragma unroll
        for (int j = 0; j < KK; ++j)
          acc[k][r] += xv[j] * owv[k * 7 + j];
    }
  }

#pragma unroll
  for (int k = 0; k < KK; ++k)
#pragma unroll
    for (int r = 0; r < 4; ++r) red[wu][lane + 64 * r][k] = acc[k][r];
  __syncthreads();

#pragma unroll
  for (int k = 0; k < KK; ++k) {
    float s = red[0][t][k] + red[1][t][k] + red[2][t][k] + red[3][t][k];
    Partial[((size_t)(cg * 7 + k) << 15) + nb + t] = s;   // coalesced
  }
}

// ---------------------------------------------------------------------------
// Kernel 2: Loc[k][n] = (l+k) + OB[k] + sum_cg Partial[cg*7+k][n] (unchanged)
// ---------------------------------------------------------------------------
__global__ __launch_bounds__(256) void loc_reduce(
    const float* __restrict__ Partial, const float* __restrict__ OB,
    float* __restrict__ Loc) {
  int n = blockIdx.x * 256 + threadIdx.x;      // grid 128 -> 32768
  int l = n & (LEN - 1);
#pragma unroll
  for (int k = 0; k < KK; ++k) {
    float s = (float)(l + k) + OB[k];
#pragma unroll
    for (int cg = 0; cg < 4; ++cg)
      s += Partial[((size_t)(cg * 7 + k) << 15) + n];
    Loc[((size_t)k << 15) + n] = s;
  }
}

// ---------------------------------------------------------------------------
// Kernel 3: weights -> bf16 A-fragments via LDS. (unchanged)
// ---------------------------------------------------------------------------
__global__ __launch_bounds__(256) void wt_build(
    const float* __restrict__ W, unsigned short* __restrict__ Wf) {
  __shared__ float Wl[16 * 32 * KK];           // 14336 B
  const int t  = threadIdx.x;
  const int ot = blockIdx.x >> 3;
  const int c  = blockIdx.x & 7;

  for (int e = t; e < 16 * 32 * KK; e += 256) {
    int o = e / 224;
    int r = e - o * 224;
    Wl[e] = W[(size_t)(ot * 16 + o) * QTOT + c * 224 + r];
  }
  __syncthreads();

  const int lane = t & 63;
  const int sg   = t >> 6;
  const int ol   = lane & 15;
  const int ig   = lane >> 4;
  for (int s = sg; s < KK; s += 4) {
    s16x8 v;
#pragma unroll
    for (int j = 0; j < 8; ++j)
      v[j] = (short)f2bf(Wl[ol * 224 + (ig * 8 + j) * KK + s]);
    int f = (ot * 8 + c) * KK + s;
    *(s16x8*)(Wf + ((size_t)f << 9) + (lane << 3)) = v;
  }
}

// ---------------------------------------------------------------------------
// Kernel 4: main MFMA GEMM (r10 fused schedule). Block = 512 threads
// (8 waves), 256 o x 64 n, grid 512 (= 2 blocks/CU). Per chunk: af frags ->
// registers FIRST, then gathers for c+1 in 8-channel quarters interleaved
// between MFMA K-steps. Double-buffered Il, 1 barrier/chunk.
// launch_bounds (512,2): 128-VGPR cap — schedule fits without spill.
// ---------------------------------------------------------------------------
__global__ __launch_bounds__(512, 2) void main_kernel(
    const float* __restrict__ X, const unsigned short* __restrict__ Wf,
    const float* __restrict__ Bias, const float* __restrict__ Loc,
    float* __restrict__ Out) {
  __shared__ unsigned short Il[2][64][LPITCH];   // 59392 B

  const int t    = threadIdx.x;
  const int lane = t & 63;
  const int w    = t >> 6;                     // 0..7
  const int n0   = blockIdx.x << 6;            // grid 512
  const int b    = n0 >> 13;
  const float* Xb = X + ((size_t)b << 21);

  const bool stager = (t < 448);
  const int nl = t & 63;
  const int kt = t >> 6;                       // 0..6 when stager

  float c0 = 0.f, c1 = 0.f;
  const float* xp = Xb;
  if (stager) {
    float locv = Loc[((size_t)kt << 15) + n0 + nl];
    int x0  = (int)floorf(locv);
    int x0c = min(max(x0, 0), LEN - 1);
    int x1c = min(max(x0 + 1, 0), LEN - 1);
    float wa = (float)x1c - locv;
    float wb = locv - (float)x0c;
    bool hi = (x0 >= LEN - 1);
    bool lo = (x0 < 0);
    c0 = (hi ? 0.f : wa) + (lo ? wb : 0.f);   // coeff of x[p0]
    c1 = (hi ? wa : 0.f) + (lo ? 0.f : wb);   // coeff of x[p0+1]
    xp = Xb + min(max(x0, 0), LEN - 2);
  }

  f32x4 acc[2][4];
#pragma unroll
  for (int a = 0; a < 2; ++a)
#pragma unroll
    for (int cc = 0; cc < 4; ++cc) acc[a][cc] = (f32x4){0.f, 0.f, 0.f, 0.f};

  const int mrow = lane & 15;
  const int quad = lane >> 4;

  float f0[8], f1[8];

#define GATHER_Q(chunk, q)                                        \
  if (stager) {                                                   \
    _Pragma("unroll")                                             \
    for (int m = 0; m < 8; ++m) {                                 \
      const float* xr = xp + ((size_t)((chunk) * 32 + (q) * 8 + m) << 13); \
      f0[m] = xr[0];                                              \
      f1[m] = xr[1];                                              \
    }                                                             \
  }

#define CVT_Q(dst, q)                                             \
  if (stager) {                                                   \
    s32x4 vv;                                                     \
    _Pragma("unroll")                                             \
    for (int m = 0; m < 4; ++m) {                                 \
      float a = c0 * f0[2 * m]     + c1 * f1[2 * m];              \
      float d = c0 * f0[2 * m + 1] + c1 * f1[2 * m + 1];          \
      vv[m] = cvt_pk_bf16(a, d);                                  \
    }                                                             \
    *(s32x4*)((dst) + nl * LPITCH + kt * 32 + (q) * 8) = vv;      \
  }

#define AFL(ttv, sv)                                              \
  (*(const s16x8*)(Wf + ((size_t)(((w * 2 + (ttv)) * 8 + c) * KK + (sv)) << 9) + (lane << 3)))

#define MSTEP(sv, a0, a1) {                                                        \
    const s16x8 b0 = *(const s16x8*)(Icur + (mrow)      * LPITCH + (sv) * 32 + quad * 8); \
    const s16x8 b1 = *(const s16x8*)(Icur + (16 + mrow) * LPITCH + (sv) * 32 + quad * 8); \
    acc[0][0] = __builtin_amdgcn_mfma_f32_16x16x32_bf16(a0, b0, acc[0][0], 0, 0, 0); \
    acc[1][0] = __builtin_amdgcn_mfma_f32_16x16x32_bf16(a1, b0, acc[1][0], 0, 0, 0); \
    acc[0][1] = __builtin_amdgcn_mfma_f32_16x16x32_bf16(a0, b1, acc[0][1], 0, 0, 0); \
    acc[1][1] = __builtin_amdgcn_mfma_f32_16x16x32_bf16(a1, b1, acc[1][1], 0, 0, 0); \
    const s16x8 b2 = *(const s16x8*)(Icur + (32 + mrow) * LPITCH + (sv) * 32 + quad * 8); \
    const s16x8 b3 = *(const s16x8*)(Icur + (48 + mrow) * LPITCH + (sv) * 32 + quad * 8); \
    acc[0][2] = __builtin_amdgcn_mfma_f32_16x16x32_bf16(a0, b2, acc[0][2], 0, 0, 0); \
    acc[1][2] = __builtin_amdgcn_mfma_f32_16x16x32_bf16(a1, b2, acc[1][2], 0, 0, 0); \
    acc[0][3] = __builtin_amdgcn_mfma_f32_16x16x32_bf16(a0, b3, acc[0][3], 0, 0, 0); \
    acc[1][3] = __builtin_amdgcn_mfma_f32_16x16x32_bf16(a1, b3, acc[1][3], 0, 0, 0); \
  }

  // prologue: stage chunk 0 into Il[0]
  {
    unsigned short* I0 = &Il[0][0][0];
    GATHER_Q(0, 0) CVT_Q(I0, 0)
    GATHER_Q(0, 1) CVT_Q(I0, 1)
    GATHER_Q(0, 2) CVT_Q(I0, 2)
    GATHER_Q(0, 3) CVT_Q(I0, 3)
  }
  __syncthreads();

  for (int c = 0; c < 8; ++c) {
    const int cur = c & 1;
    const unsigned short* Icur = &Il[cur][0][0];
    unsigned short*       Inxt = &Il[cur ^ 1][0][0];

    // af fragments for s=0..3 FIRST (before any gather this chunk)
    s16x8 afA[2][4];
#pragma unroll
    for (int tt = 0; tt < 2; ++tt)
#pragma unroll
      for (int s = 0; s < 4; ++s) afA[tt][s] = AFL(tt, s);
    __builtin_amdgcn_sched_barrier(0);

    if (c < 7) { GATHER_Q(c + 1, 0) }
    MSTEP(0, afA[0][0], afA[1][0])
    if (c < 7) { CVT_Q(Inxt, 0) GATHER_Q(c + 1, 1) }
    MSTEP(1, afA[0][1], afA[1][1])

    // af fragments for s=4..6 (before gather quarters 2,3)
    s16x8 afB[2][3];
#pragma unroll
    for (int tt = 0; tt < 2; ++tt)
#pragma unroll
      for (int s = 0; s < 3; ++s) afB[tt][s] = AFL(tt, 4 + s);
    __builtin_amdgcn_sched_barrier(0);

    if (c < 7) { CVT_Q(Inxt, 1) GATHER_Q(c + 1, 2) }
    MSTEP(2, afA[0][2], afA[1][2])
    if (c < 7) { CVT_Q(Inxt, 2) GATHER_Q(c + 1, 3) }
    MSTEP(3, afA[0][3], afA[1][3])
    if (c < 7) { CVT_Q(Inxt, 3) }
    MSTEP(4, afB[0][0], afB[1][0])
    MSTEP(5, afB[0][1], afB[1][1])
    MSTEP(6, afB[0][2], afB[1][2])
    if (c < 7) __syncthreads();
  }
#undef GATHER_Q
#undef CVT_Q
#undef AFL
#undef MSTEP

  // epilogue: D row m = quad*4+r (o), col = mrow (l)
  const int lbase = (n0 & (LEN - 1)) + mrow;
#pragma unroll
  for (int tt = 0; tt < 2; ++tt) {
    const int obase = (w * 2 + tt) * 16 + quad * 4;
#pragma unroll
    for (int r = 0; r < 4; ++r) {
      const int o = obase + r;
      const float bv = Bias[o];
      float* orow = Out + (((size_t)(b * COUT + o)) << 13) + lbase;
#pragma unroll
      for (int nt = 0; nt < 4; ++nt)
        orow[nt * 16] = acc[tt][nt][r] + bv;
    }
  }
}

extern "C" void kernel_launch(void* const* d_in, const int* in_sizes, int n_in,
                              void* d_out, int out_size, void* d_ws, size_t ws_size,
                              hipStream_t stream) {
  const float* X    = (const float*)d_in[0];   // (4,256,8192)
  const float* W    = (const float*)d_in[1];   // (256,256,7)
  const float* Bias = (const float*)d_in[2];   // (256,)
  const float* OW   = (const float*)d_in[3];   // (7,256,7)
  const float* OB   = (const float*)d_in[4];   // (7,)
  float* Out = (float*)d_out;                  // (4,256,8192)

  // ws: Loc (0.92 MB) | Wf (0.92 MB) | Partial (3.5 MB)  = 5.4 MB
  float* Loc = (float*)d_ws;
  unsigned short* Wf = (unsigned short*)(Loc + (size_t)NTOT * KK);
  float* Partial = (float*)(Wf + (size_t)COUT * QTOT);

  loc_partial<<<4 * 128, 256, 0, stream>>>(X, OW, Partial);
  loc_reduce<<<NTOT / 256, 256, 0, stream>>>(Partial, OB, Loc);
  wt_build<<<128, 256, 0, stream>>>(W, Wf);
  main_kernel<<<NTOT / 64, 512, 0, stream>>>(X, Wf, Bias, Loc, Out);
}